// Round 7
// baseline (57.813 us; speedup 1.0000x reference)
//
#include <hip/hip_runtime.h>

// EVI fused kernel, round 7: 8-way channel split -> 2 block generations per CU.
// - 8 threads co-own one float4 voxel group; each owns 8 of 64 channels.
//   (R2-R6's 4-way split = 2048 blocks = exactly ONE residency generation ->
//   device-wide load/compute/store convoy with no backfill. 4096 blocks gives
//   the CU scheduler a second generation to overlap into the compute/store tail.)
// - Reduce across 8 chunks via __shfl_xor(8/16/32).
// - Scan runs on all 8 chunk-threads (elements duplicated on chunk&3) - VALU
//   has headroom (18% busy); redistribution via xor-shuffles 8/16 + cndmask swaps.
// - NO multi-generation in-thread pipelining (R4/R5: spills, 650 MB scratch).
// - Non-temporal stores keep `out` from evicting x out of the 256 MB L3.

constexpr int kInCh    = 64;
constexpr int kCls     = 4;
constexpr int kProto   = 20;
constexpr long kSpatial = 64L * 64L * 64L;   // 262144, D contiguous
constexpr int kVec     = 4;                   // float4 voxels per group
constexpr int kChunk   = 8;                   // channels per thread
constexpr int kNCh     = 8;                   // chunk-threads per voxel group

typedef float f32x4 __attribute__((ext_vector_type(4)));

__global__ __launch_bounds__(256) void evi_fused_kernel(
    const float* __restrict__ x,
    const float* __restrict__ w_to,    // (CLS, IN_CH)
    const float* __restrict__ b_to,    // (CLS,)
    const float* __restrict__ w_from,  // (IN_CH, CLS)
    const float* __restrict__ b_from,  // (IN_CH,)
    const float* __restrict__ Wm,      // (PROTO, CLS)
    const float* __restrict__ BETA,    // (PROTO, CLS)
    const float* __restrict__ alpha,   // (PROTO, 1)
    const float* __restrict__ gamma,   // (PROTO, 1)
    float* __restrict__ out)
{
    __shared__ float s_wt[kCls * kInCh];   // w_to[o][c]
    __shared__ float s_wf[kInCh * kCls];   // w_from[i][c]
    __shared__ float s_bf[kInCh];
    __shared__ float s_bto[kCls];
    __shared__ float s_W[kProto][kCls];
    __shared__ float s_U[kProto][kCls];
    __shared__ float s_ap[kProto];
    __shared__ float s_g2[kProto];

    const int t = threadIdx.x;

    // ---- stage weights / per-proto params into LDS (once per block) ----
    s_wt[t] = w_to[t];
    s_wf[t] = w_from[t];
    if (t < kInCh) s_bf[t] = b_from[t];
    if (t < kCls)  s_bto[t] = b_to[t];
    if (t < kProto) {
        float bsq[kCls];
        float sum = 0.f;
        #pragma unroll
        for (int c = 0; c < kCls; ++c) {
            const float bb = BETA[t * kCls + c];
            bsq[c] = bb * bb;
            sum += bsq[c];
        }
        const float inv = 1.0f / sum;
        #pragma unroll
        for (int c = 0; c < kCls; ++c) {
            s_U[t][c] = bsq[c] * inv;
            s_W[t][c] = Wm[t * kCls + c];
        }
        s_ap[t] = 0.99f / (1.0f + expf(-alpha[t]));
        const float g = gamma[t];
        s_g2[t] = g * g;
    }
    __syncthreads();

    // ---- lane decomposition: 8 voxel groups per wave, 8 chunk-threads each ----
    const int tid   = blockIdx.x * blockDim.x + t;
    const int wave  = tid >> 6;
    const int lane  = tid & 63;
    const int chunk = lane >> 3;                 // 0..7 -> channels [chunk*8, chunk*8+8)
    const int sub   = lane & 7;                  // voxel-group within wave
    const int c0    = chunk * kChunk;
    const int q3    = chunk & 3;                 // scan element owned by this thread
    const bool cb1  = (chunk & 1) != 0;
    const bool cb2  = (chunk & 2) != 0;

    const int vgPerBatch = (int)(kSpatial / kVec);   // 65536
    const int vg = wave * kNCh + sub;                // [0, 131072)
    const int b = vg >> 16;
    const int r = vg & (vgPerBatch - 1);
    const size_t base = (size_t)b * kInCh * kSpatial + (size_t)r * kVec;

    // ---- load this thread's 8 channels ----
    f32x4 xa[kChunk];
    #pragma unroll
    for (int j = 0; j < kChunk; ++j)
        xa[j] = *reinterpret_cast<const f32x4*>(x + base + (size_t)(c0 + j) * kSpatial);

    // ---- partial ev over 8 channels ----
    float ev[kCls][kVec];
    #pragma unroll
    for (int o = 0; o < kCls; ++o)
        #pragma unroll
        for (int v = 0; v < kVec; ++v) ev[o][v] = 0.0f;

    #pragma unroll
    for (int j = 0; j < kChunk; ++j) {
        const int c = c0 + j;
        #pragma unroll
        for (int o = 0; o < kCls; ++o) {
            const float w = s_wt[o * kInCh + c];
            ev[o][0] += xa[j].x * w;
            ev[o][1] += xa[j].y * w;
            ev[o][2] += xa[j].z * w;
            ev[o][3] += xa[j].w * w;
        }
    }

    // ---- cross-chunk reduce (8 chunk-threads share a voxel group) ----
    #pragma unroll
    for (int o = 0; o < kCls; ++o)
        #pragma unroll
        for (int v = 0; v < kVec; ++v) {
            float e = ev[o][v];
            e += __shfl_xor(e, 8, 64);
            e += __shfl_xor(e, 16, 64);
            e += __shfl_xor(e, 32, 64);
            ev[o][v] = e + s_bto[o];
        }

    // ---- select this thread's vec element (v = chunk&3), compile-time indices ----
    float evs[kCls];
    #pragma unroll
    for (int c = 0; c < kCls; ++c) {
        float e = ev[c][0];
        e = (q3 == 1) ? ev[c][1] : e;
        e = (q3 == 2) ? ev[c][2] : e;
        e = (q3 == 3) ? ev[c][3] : e;
        evs[c] = e;
    }

    // ---- 20-proto evidence scan (element q3; duplicated on chunk and chunk+4) ----
    float mkc[kCls];
    float mk5 = 1.0f;
    #pragma unroll
    for (int c = 0; c < kCls; ++c) mkc[c] = 0.0f;
    for (int k = 0; k < kProto; ++k) {
        float d = 0.0f;
        #pragma unroll
        for (int c = 0; c < kCls; ++c) {
            const float df = evs[c] - s_W[k][c];
            d += df * df;
        }
        d *= 0.5f;
        const float s  = s_ap[k] * __expf(-s_g2[k] * d);
        const float m5 = 1.0f - s;
        const float old5 = mk5;
        #pragma unroll
        for (int c = 0; c < kCls; ++c) {
            const float mc = s_U[k][c] * s;
            mkc[c] = mkc[c] * (mc + m5) + mc * old5;
        }
        mk5 = old5 * m5;
    }

    // ---- normalize ----
    float K = mk5;
    #pragma unroll
    for (int c = 0; c < kCls; ++c) K += mkc[c];
    const float invK = 1.0f / K;
    float evid_s[kCls];
    #pragma unroll
    for (int c = 0; c < kCls; ++c) evid_s[c] = (mkc[c] + mk5) * invK;

    // ---- redistribute: thread holds element q3; gather elements q3^1,q3^2,q3^3
    //      via lane-xor 8/16 shuffles, then unscramble with chunk-uniform swaps ----
    float evid[kCls][kVec];
    #pragma unroll
    for (int c = 0; c < kCls; ++c) {
        const float e0  = evid_s[c];                // element q3
        const float s1  = __shfl_xor(e0, 8, 64);    // element q3^1
        const float s2  = __shfl_xor(e0, 16, 64);   // element q3^2
        const float s3  = __shfl_xor(s1, 16, 64);   // element q3^3
        // stage 1: chunk&1 -> swap (e0,s1), (s2,s3)
        const float a0 = cb1 ? s1 : e0;
        const float a1 = cb1 ? e0 : s1;
        const float a2 = cb1 ? s3 : s2;
        const float a3 = cb1 ? s2 : s3;
        // stage 2: chunk&2 -> swap (a0,a2), (a1,a3)
        evid[c][0] = cb2 ? a2 : a0;
        evid[c][1] = cb2 ? a3 : a1;
        evid[c][2] = cb2 ? a0 : a2;
        evid[c][3] = cb2 ? a1 : a3;
    }

    // ---- back-projection: this thread's 8 output channels, nt stores ----
    #pragma unroll
    for (int j = 0; j < kChunk; ++j) {
        const int o = c0 + j;
        const float w0 = s_wf[o * kCls + 0];
        const float w1 = s_wf[o * kCls + 1];
        const float w2 = s_wf[o * kCls + 2];
        const float w3 = s_wf[o * kCls + 3];
        const float bo = s_bf[o];
        f32x4 acc;
        acc.x = bo + evid[0][0]*w0 + evid[1][0]*w1 + evid[2][0]*w2 + evid[3][0]*w3;
        acc.y = bo + evid[0][1]*w0 + evid[1][1]*w1 + evid[2][1]*w2 + evid[3][1]*w3;
        acc.z = bo + evid[0][2]*w0 + evid[1][2]*w1 + evid[2][2]*w2 + evid[3][2]*w3;
        acc.w = bo + evid[0][3]*w0 + evid[1][3]*w1 + evid[2][3]*w2 + evid[3][3]*w3;
        __builtin_nontemporal_store(acc, reinterpret_cast<f32x4*>(out + base + (size_t)o * kSpatial));
    }
}

extern "C" void kernel_launch(void* const* d_in, const int* in_sizes, int n_in,
                              void* d_out, int out_size, void* d_ws, size_t ws_size,
                              hipStream_t stream) {
    const float* x      = (const float*)d_in[0];
    const float* w_to   = (const float*)d_in[1];
    const float* b_to   = (const float*)d_in[2];
    const float* w_from = (const float*)d_in[3];
    const float* b_from = (const float*)d_in[4];
    const float* Wm     = (const float*)d_in[5];
    const float* BETA   = (const float*)d_in[6];
    const float* alpha  = (const float*)d_in[7];
    const float* gamma  = (const float*)d_in[8];
    float* out = (float*)d_out;

    // 131072 voxel-groups x 8 chunk-threads = 1048576 threads -> 4096 blocks
    const int block = 256;
    const int grid  = 4096;
    evi_fused_kernel<<<grid, block, 0, stream>>>(x, w_to, b_to, w_from, b_from,
                                                 Wm, BETA, alpha, gamma, out);
}

// Round 8
// 49.582 us; speedup vs baseline: 1.1660x; 1.1660x over previous
//
#include <hip/hip_runtime.h>

// EVI fused kernel, round 8: float2 voxel-pair per thread, all 64 channels.
// Rationale (R7 post-mortem): effective HBM BW tracks per-wave-load contiguous
// segment size (128B->57.8us, 256B->51.4us). This layout gives 512B contiguous
// per channel per wave-load (64 lanes x 8B), with ZERO cross-lane ops:
// - no shuffles (tests the phantom 16KB LDS + 1.77M bank-conflict hypothesis),
// - no scan duplication (each thread scans its own 2 voxels),
// - 262144 threads = 1024 blocks = 16 waves/CU (R3's effective occupancy was
//   ~10.5 waves/CU, so grid supply is not the binding constraint).
// - NO in-thread multi-generation pipelining (R4/R5: 650 MB scratch spills).
// - Non-temporal stores keep `out` from evicting x out of the 256 MB L3.

constexpr int kInCh    = 64;
constexpr int kCls     = 4;
constexpr int kProto   = 20;
constexpr long kSpatial = 64L * 64L * 64L;   // 262144, D contiguous
constexpr int kPairsPerBatch = (int)(kSpatial / 2);   // 131072 float2 pairs

typedef float f32x2 __attribute__((ext_vector_type(2)));

__global__ __launch_bounds__(256) void evi_fused_kernel(
    const float* __restrict__ x,
    const float* __restrict__ w_to,    // (CLS, IN_CH)
    const float* __restrict__ b_to,    // (CLS,)
    const float* __restrict__ w_from,  // (IN_CH, CLS)
    const float* __restrict__ b_from,  // (IN_CH,)
    const float* __restrict__ Wm,      // (PROTO, CLS)
    const float* __restrict__ BETA,    // (PROTO, CLS)
    const float* __restrict__ alpha,   // (PROTO, 1)
    const float* __restrict__ gamma,   // (PROTO, 1)
    float* __restrict__ out)
{
    __shared__ float s_wt[kCls * kInCh];   // w_to[o][c]
    __shared__ float s_wf[kInCh * kCls];   // w_from[i][c]
    __shared__ float s_bf[kInCh];
    __shared__ float s_bto[kCls];
    __shared__ float s_W[kProto][kCls];
    __shared__ float s_U[kProto][kCls];
    __shared__ float s_ap[kProto];
    __shared__ float s_g2[kProto];

    const int t = threadIdx.x;

    // ---- stage weights / per-proto params into LDS (once per block) ----
    s_wt[t] = w_to[t];
    s_wf[t] = w_from[t];
    if (t < kInCh) s_bf[t] = b_from[t];
    if (t < kCls)  s_bto[t] = b_to[t];
    if (t < kProto) {
        float bsq[kCls];
        float sum = 0.f;
        #pragma unroll
        for (int c = 0; c < kCls; ++c) {
            const float bb = BETA[t * kCls + c];
            bsq[c] = bb * bb;
            sum += bsq[c];
        }
        const float inv = 1.0f / sum;
        #pragma unroll
        for (int c = 0; c < kCls; ++c) {
            s_U[t][c] = bsq[c] * inv;
            s_W[t][c] = Wm[t * kCls + c];
        }
        s_ap[t] = 0.99f / (1.0f + expf(-alpha[t]));
        const float g = gamma[t];
        s_g2[t] = g * g;
    }
    __syncthreads();

    // ---- one float2 voxel-pair per thread, all 64 channels ----
    const int tid = blockIdx.x * blockDim.x + t;      // [0, 262144)
    const int b   = tid >> 17;                        // tid / 131072
    const int r   = tid & (kPairsPerBatch - 1);
    const size_t base = (size_t)b * kInCh * kSpatial + (size_t)r * 2;

    // ---- ev = w_to . x + b_to (2 voxels) ----
    float ev[kCls][2];
    #pragma unroll
    for (int o = 0; o < kCls; ++o) {
        ev[o][0] = s_bto[o];
        ev[o][1] = s_bto[o];
    }

    #pragma unroll
    for (int c = 0; c < kInCh; ++c) {
        const f32x2 xv = *reinterpret_cast<const f32x2*>(x + base + (size_t)c * kSpatial);
        #pragma unroll
        for (int o = 0; o < kCls; ++o) {
            const float w = s_wt[o * kInCh + c];
            ev[o][0] += xv.x * w;
            ev[o][1] += xv.y * w;
        }
    }

    // ---- 20-proto evidence scan (2 voxels, all in registers, static indices) ----
    float mkc[kCls][2];
    float mk5[2] = {1.0f, 1.0f};
    #pragma unroll
    for (int c = 0; c < kCls; ++c) { mkc[c][0] = 0.0f; mkc[c][1] = 0.0f; }

    for (int k = 0; k < kProto; ++k) {
        const float ap = s_ap[k];
        const float g2 = s_g2[k];
        float Wk[kCls], Uk[kCls];
        #pragma unroll
        for (int c = 0; c < kCls; ++c) { Wk[c] = s_W[k][c]; Uk[c] = s_U[k][c]; }
        #pragma unroll
        for (int v = 0; v < 2; ++v) {
            float d = 0.0f;
            #pragma unroll
            for (int c = 0; c < kCls; ++c) {
                const float df = ev[c][v] - Wk[c];
                d += df * df;
            }
            d *= 0.5f;
            const float s  = ap * __expf(-g2 * d);
            const float m5 = 1.0f - s;
            const float old5 = mk5[v];
            #pragma unroll
            for (int c = 0; c < kCls; ++c) {
                const float mc = Uk[c] * s;
                mkc[c][v] = mkc[c][v] * (mc + m5) + mc * old5;
            }
            mk5[v] = old5 * m5;
        }
    }

    // ---- normalize: evid[c] = (mkc[c] + mk5) / K ----
    float evid[kCls][2];
    #pragma unroll
    for (int v = 0; v < 2; ++v) {
        float K = mk5[v];
        #pragma unroll
        for (int c = 0; c < kCls; ++c) K += mkc[c][v];
        const float inv = 1.0f / K;
        #pragma unroll
        for (int c = 0; c < kCls; ++c) evid[c][v] = (mkc[c][v] + mk5[v]) * inv;
    }

    // ---- out = w_from . evid + b_from (64 channels, nt float2 stores) ----
    #pragma unroll
    for (int o = 0; o < kInCh; ++o) {
        const float w0 = s_wf[o * kCls + 0];
        const float w1 = s_wf[o * kCls + 1];
        const float w2 = s_wf[o * kCls + 2];
        const float w3 = s_wf[o * kCls + 3];
        const float bo = s_bf[o];
        f32x2 acc;
        acc.x = bo + evid[0][0]*w0 + evid[1][0]*w1 + evid[2][0]*w2 + evid[3][0]*w3;
        acc.y = bo + evid[0][1]*w0 + evid[1][1]*w1 + evid[2][1]*w2 + evid[3][1]*w3;
        __builtin_nontemporal_store(acc, reinterpret_cast<f32x2*>(out + base + (size_t)o * kSpatial));
    }
}

extern "C" void kernel_launch(void* const* d_in, const int* in_sizes, int n_in,
                              void* d_out, int out_size, void* d_ws, size_t ws_size,
                              hipStream_t stream) {
    const float* x      = (const float*)d_in[0];
    const float* w_to   = (const float*)d_in[1];
    const float* b_to   = (const float*)d_in[2];
    const float* w_from = (const float*)d_in[3];
    const float* b_from = (const float*)d_in[4];
    const float* Wm     = (const float*)d_in[5];
    const float* BETA   = (const float*)d_in[6];
    const float* alpha  = (const float*)d_in[7];
    const float* gamma  = (const float*)d_in[8];
    float* out = (float*)d_out;

    // 262144 voxel-pairs -> 262144 threads -> 1024 blocks
    const int block = 256;
    const int grid  = 1024;
    evi_fused_kernel<<<grid, block, 0, stream>>>(x, w_to, b_to, w_from, b_from,
                                                 Wm, BETA, alpha, gamma, out);
}

// Round 9
// 47.039 us; speedup vs baseline: 1.2290x; 1.0541x over previous
//
#include <hip/hip_runtime.h>

// EVI fused kernel, round 9: R8 + forced load-front via sched_barrier.
// R8 (49.6us) analysis: memory-latency-limited by bytes-in-flight (~3.8 KB/CU
// vs ~9 KB needed per Little's law). The compiler chose 96 VGPR and capped
// in-flight loads at ~30. Fix: issue ALL 64 channel loads (512 B/lane-wave)
// before any FMA, fenced with __builtin_amdgcn_sched_barrier(0) so the
// scheduler cannot sink loads below consumption (it silently did so in R6).
// Load registers are all dead before the scan -> no R4/R5-style epilogue spill.
// Everything else identical to R8 (float2/thread, 512B segments, nt stores,
// no cross-lane ops, 1024 blocks).

constexpr int kInCh    = 64;
constexpr int kCls     = 4;
constexpr int kProto   = 20;
constexpr long kSpatial = 64L * 64L * 64L;   // 262144, D contiguous
constexpr int kPairsPerBatch = (int)(kSpatial / 2);   // 131072 float2 pairs

typedef float f32x2 __attribute__((ext_vector_type(2)));

__global__ __launch_bounds__(256) void evi_fused_kernel(
    const float* __restrict__ x,
    const float* __restrict__ w_to,    // (CLS, IN_CH)
    const float* __restrict__ b_to,    // (CLS,)
    const float* __restrict__ w_from,  // (IN_CH, CLS)
    const float* __restrict__ b_from,  // (IN_CH,)
    const float* __restrict__ Wm,      // (PROTO, CLS)
    const float* __restrict__ BETA,    // (PROTO, CLS)
    const float* __restrict__ alpha,   // (PROTO, 1)
    const float* __restrict__ gamma,   // (PROTO, 1)
    float* __restrict__ out)
{
    __shared__ float s_wt[kCls * kInCh];   // w_to[o][c]
    __shared__ float s_wf[kInCh * kCls];   // w_from[i][c]
    __shared__ float s_bf[kInCh];
    __shared__ float s_bto[kCls];
    __shared__ float s_W[kProto][kCls];
    __shared__ float s_U[kProto][kCls];
    __shared__ float s_ap[kProto];
    __shared__ float s_g2[kProto];

    const int t = threadIdx.x;

    // ---- stage weights / per-proto params into LDS (once per block) ----
    s_wt[t] = w_to[t];
    s_wf[t] = w_from[t];
    if (t < kInCh) s_bf[t] = b_from[t];
    if (t < kCls)  s_bto[t] = b_to[t];
    if (t < kProto) {
        float bsq[kCls];
        float sum = 0.f;
        #pragma unroll
        for (int c = 0; c < kCls; ++c) {
            const float bb = BETA[t * kCls + c];
            bsq[c] = bb * bb;
            sum += bsq[c];
        }
        const float inv = 1.0f / sum;
        #pragma unroll
        for (int c = 0; c < kCls; ++c) {
            s_U[t][c] = bsq[c] * inv;
            s_W[t][c] = Wm[t * kCls + c];
        }
        s_ap[t] = 0.99f / (1.0f + expf(-alpha[t]));
        const float g = gamma[t];
        s_g2[t] = g * g;
    }
    __syncthreads();

    // ---- one float2 voxel-pair per thread, all 64 channels ----
    const int tid = blockIdx.x * blockDim.x + t;      // [0, 262144)
    const int b   = tid >> 17;                        // tid / 131072
    const int r   = tid & (kPairsPerBatch - 1);
    const size_t base = (size_t)b * kInCh * kSpatial + (size_t)r * 2;

    // ---- issue ALL 64 loads back-to-back; fence so nothing sinks below ----
    f32x2 xv[kInCh];
    #pragma unroll
    for (int c = 0; c < kInCh; ++c)
        xv[c] = *reinterpret_cast<const f32x2*>(x + base + (size_t)c * kSpatial);
    __builtin_amdgcn_sched_barrier(0);   // all 64 VMEM issued before any VALU below

    // ---- ev = w_to . x + b_to (2 voxels); consumes xv in issue order ----
    float ev[kCls][2];
    #pragma unroll
    for (int o = 0; o < kCls; ++o) {
        ev[o][0] = s_bto[o];
        ev[o][1] = s_bto[o];
    }
    #pragma unroll
    for (int c = 0; c < kInCh; ++c) {
        #pragma unroll
        for (int o = 0; o < kCls; ++o) {
            const float w = s_wt[o * kInCh + c];
            ev[o][0] += xv[c].x * w;
            ev[o][1] += xv[c].y * w;
        }
    }

    // ---- 20-proto evidence scan (2 voxels, all in registers, static indices) ----
    float mkc[kCls][2];
    float mk5[2] = {1.0f, 1.0f};
    #pragma unroll
    for (int c = 0; c < kCls; ++c) { mkc[c][0] = 0.0f; mkc[c][1] = 0.0f; }

    for (int k = 0; k < kProto; ++k) {
        const float ap = s_ap[k];
        const float g2 = s_g2[k];
        float Wk[kCls], Uk[kCls];
        #pragma unroll
        for (int c = 0; c < kCls; ++c) { Wk[c] = s_W[k][c]; Uk[c] = s_U[k][c]; }
        #pragma unroll
        for (int v = 0; v < 2; ++v) {
            float d = 0.0f;
            #pragma unroll
            for (int c = 0; c < kCls; ++c) {
                const float df = ev[c][v] - Wk[c];
                d += df * df;
            }
            d *= 0.5f;
            const float s  = ap * __expf(-g2 * d);
            const float m5 = 1.0f - s;
            const float old5 = mk5[v];
            #pragma unroll
            for (int c = 0; c < kCls; ++c) {
                const float mc = Uk[c] * s;
                mkc[c][v] = mkc[c][v] * (mc + m5) + mc * old5;
            }
            mk5[v] = old5 * m5;
        }
    }

    // ---- normalize: evid[c] = (mkc[c] + mk5) / K ----
    float evid[kCls][2];
    #pragma unroll
    for (int v = 0; v < 2; ++v) {
        float K = mk5[v];
        #pragma unroll
        for (int c = 0; c < kCls; ++c) K += mkc[c][v];
        const float inv = 1.0f / K;
        #pragma unroll
        for (int c = 0; c < kCls; ++c) evid[c][v] = (mkc[c][v] + mk5[v]) * inv;
    }

    // ---- out = w_from . evid + b_from (64 channels, nt float2 stores) ----
    #pragma unroll
    for (int o = 0; o < kInCh; ++o) {
        const float w0 = s_wf[o * kCls + 0];
        const float w1 = s_wf[o * kCls + 1];
        const float w2 = s_wf[o * kCls + 2];
        const float w3 = s_wf[o * kCls + 3];
        const float bo = s_bf[o];
        f32x2 acc;
        acc.x = bo + evid[0][0]*w0 + evid[1][0]*w1 + evid[2][0]*w2 + evid[3][0]*w3;
        acc.y = bo + evid[0][1]*w0 + evid[1][1]*w1 + evid[2][1]*w2 + evid[3][1]*w3;
        __builtin_nontemporal_store(acc, reinterpret_cast<f32x2*>(out + base + (size_t)o * kSpatial));
    }
}

extern "C" void kernel_launch(void* const* d_in, const int* in_sizes, int n_in,
                              void* d_out, int out_size, void* d_ws, size_t ws_size,
                              hipStream_t stream) {
    const float* x      = (const float*)d_in[0];
    const float* w_to   = (const float*)d_in[1];
    const float* b_to   = (const float*)d_in[2];
    const float* w_from = (const float*)d_in[3];
    const float* b_from = (const float*)d_in[4];
    const float* Wm     = (const float*)d_in[5];
    const float* BETA   = (const float*)d_in[6];
    const float* alpha  = (const float*)d_in[7];
    const float* gamma  = (const float*)d_in[8];
    float* out = (float*)d_out;

    // 262144 voxel-pairs -> 262144 threads -> 1024 blocks
    const int block = 256;
    const int grid  = 1024;
    evi_fused_kernel<<<grid, block, 0, stream>>>(x, w_to, b_to, w_from, b_from,
                                                 Wm, BETA, alpha, gamma, out);
}